// Round 13
// baseline (894.984 us; speedup 1.0000x reference)
//
#include <hip/hip_runtime.h>
#include <stdint.h>
#include <math.h>

#define BB 512
#define RR 20
#define LL 50
#define DD 64
#define PP 2
#define KK 10
#define IN_DIM 256   // 2*P*D
#define VV 50000
#define NEBLK 1280   // embed blocks (16 reviews each)
#define NTBLK 1563   // table-GEMM blocks (32 words each)

// ---------------- threefry2x32 (bit-exact JAX) ----------------
__device__ __forceinline__ uint32_t rotl32(uint32_t v, int d) {
  return (v << d) | (v >> (32 - d));
}

__device__ __forceinline__ void tf2x32(uint32_t k0, uint32_t k1,
                                       uint32_t x0, uint32_t x1,
                                       uint32_t& o0, uint32_t& o1) {
  uint32_t ks0 = k0, ks1 = k1, ks2 = k0 ^ k1 ^ 0x1BD11BDAu;
  x0 += ks0; x1 += ks1;
#define TF_RND(r) { x0 += x1; x1 = rotl32(x1, r); x1 ^= x0; }
  TF_RND(13) TF_RND(15) TF_RND(26) TF_RND(6)
  x0 += ks1; x1 += ks2 + 1u;
  TF_RND(17) TF_RND(29) TF_RND(16) TF_RND(24)
  x0 += ks2; x1 += ks0 + 2u;
  TF_RND(13) TF_RND(15) TF_RND(26) TF_RND(6)
  x0 += ks0; x1 += ks1 + 3u;
  TF_RND(17) TF_RND(29) TF_RND(16) TF_RND(24)
  x0 += ks1; x1 += ks2 + 4u;
  TF_RND(13) TF_RND(15) TF_RND(26) TF_RND(6)
  x0 += ks2; x1 += ks0 + 5u;
#undef TF_RND
  o0 = x0; o1 = x1;
}

__device__ __forceinline__ float wave_sum(float v) {
  for (int off = 32; off; off >>= 1) v += __shfl_xor(v, off, 64);
  return v;
}
__device__ __forceinline__ float wave_max(float v) {
  for (int off = 32; off; off >>= 1) v = fmaxf(v, __shfl_xor(v, off, 64));
  return v;
}

// ---------------- K0: transpose the 64x64 weight matrices ----------------
__global__ __launch_bounds__(256) void transpose_w(
    const float* __restrict__ w1, const float* __restrict__ w2,
    const float* __restrict__ ra, const float* __restrict__ wa,
    const float* __restrict__ ma,
    float* __restrict__ w1T, float* __restrict__ w2T,
    float* __restrict__ raT, float* __restrict__ waT,
    float* __restrict__ maT) {
  int i = blockIdx.x * 256 + threadIdx.x;
  if (i < DD * DD) {
    int r = i >> 6, c = i & 63;
    w1T[c * DD + r] = w1[i];
    w2T[c * DD + r] = w2[i];
    raT[c * DD + r] = ra[i];
    waT[c * DD + r] = wa[i];
    maT[c * DD + r] = ma[i];
  }
}

// ---------------- K1: FUSED embed_gate + build_tables ----------------
// grid = NEBLK + NTBLK blocks, 256 threads. LDS = 25.2 KB; with
// __launch_bounds__(256,6) VGPR is capped at ~85 -> 6 blocks/CU (24 waves).
//   bid <  NEBLK : embed+gating (16 reviews; latency-bound gather)
//   bid >= NEBLK : table GEMM, 32-word tile (VALU-bound) — co-resident filler.
__global__ __launch_bounds__(256, 6) void tables_embed(
    const int* __restrict__ uidx, const int* __restrict__ iidx,
    const float* __restrict__ emb,
    const float* __restrict__ w1T, const float* __restrict__ w2T,
    const float* __restrict__ b2, const float* __restrict__ bg,
    const float* __restrict__ waT, const float* __restrict__ wa_b,
    const float* __restrict__ maT,
    float* __restrict__ u_rev, float* __restrict__ i_rev,
    float* __restrict__ E1, float* __restrict__ E2) {
  __shared__ float A[DD * 36];    // AsT[k][w] (32 words, pad 36); reused as RsT
  __shared__ float Bs[DD * DD];   // B[k][d] unpadded (reads are broadcast/2-way)
  int tid = threadIdx.x;
  int bid = blockIdx.x;

  if (bid < NEBLK) {
    // ======== embed + gating (R10 code, bit-identical math) ========
    int* idxs = (int*)A;                       // 800 ints
    float (*us)[68] = (float(*)[68])(A + 800); // 16 x 68 floats (1888 <= 2304)
    int isItem = (bid >= 640);
    const int* src = isItem ? (iidx + (size_t)(bid - 640) * 16 * LL)
                            : (uidx + (size_t)bid * 16 * LL);
    for (int i = tid; i < 16 * LL; i += 256) idxs[i] = src[i];
    __syncthreads();
    int w = tid >> 6, lane = tid & 63;
    int grp = lane >> 4, q = lane & 15;
    int revl = w * 4 + grp;
    const int* myidx = idxs + revl * LL;
    float4 acc = {0.f, 0.f, 0.f, 0.f};
#pragma unroll
    for (int l = 0; l < LL; ++l) {             // l-sequential (matches ref)
      int v = myidx[l];
      float4 e4 = *reinterpret_cast<const float4*>(&emb[(size_t)v * DD + q * 4]);
      acc.x += e4.x; acc.y += e4.y; acc.z += e4.z; acc.w += e4.w;
    }
    *reinterpret_cast<float4*>(&us[revl][q * 4]) = acc;
    __syncthreads();
    float4 d1 = {0.f, 0.f, 0.f, 0.f}, d2 = {0.f, 0.f, 0.f, 0.f};
    for (int e = 0; e < DD; ++e) {
      float xv = us[revl][e];                  // LDS broadcast
      float4 w1v = *reinterpret_cast<const float4*>(&w1T[e * DD + q * 4]);
      float4 w2v = *reinterpret_cast<const float4*>(&w2T[e * DD + q * 4]);
      d1.x += xv * w1v.x; d1.y += xv * w1v.y; d1.z += xv * w1v.z; d1.w += xv * w1v.w;
      d2.x += xv * w2v.x; d2.y += xv * w2v.y; d2.z += xv * w2v.z; d2.w += xv * w2v.w;
    }
    float4 b2v = *reinterpret_cast<const float4*>(&b2[q * 4]);
    float4 bgv = *reinterpret_cast<const float4*>(&bg[q * 4]);
    float4 val;
    val.x = 1.f / (1.f + expf(-d1.x)) + bgv.x * tanhf(d2.x + b2v.x);
    val.y = 1.f / (1.f + expf(-d1.y)) + bgv.y * tanhf(d2.y + b2v.y);
    val.z = 1.f / (1.f + expf(-d1.z)) + bgv.z * tanhf(d2.z + b2v.z);
    val.w = 1.f / (1.f + expf(-d1.w)) + bgv.w * tanhf(d2.w + b2v.w);
    int gid = bid * 16 + revl;
    int t = gid - isItem * (BB * RR);
    float* dst = isItem ? i_rev : u_rev;
    *reinterpret_cast<float4*>(&dst[(size_t)t * DD + q * 4]) = val;
    return;
  }

  // ======== table GEMM (32-word tile): E1 = relu(emb@waT+b), E2 = E1@maT ========
  int v0 = (bid - NEBLK) * 32;
  {
    // stage A transposed: thread -> (wr = word 0..31, qk = 0..7 covering 8 dims)
    int wr = tid & 31;
    int qk = tid >> 5;             // 0..7
    int v = v0 + wr;
    for (int rep = 0; rep < 2; ++rep) {
      int k0 = qk * 8 + rep * 4;
      float4 e4 = {0.f, 0.f, 0.f, 0.f};
      if (v < VV) e4 = *reinterpret_cast<const float4*>(&emb[(size_t)v * DD + k0]);
      A[(k0 + 0) * 36 + wr] = e4.x;
      A[(k0 + 1) * 36 + wr] = e4.y;
      A[(k0 + 2) * 36 + wr] = e4.z;
      A[(k0 + 3) * 36 + wr] = e4.w;
    }
  }
  for (int i = tid; i < DD * 16; i += 256) {
    int k = i >> 4, c = i & 15;
    *reinterpret_cast<float4*>(&Bs[k * DD + c * 4]) =
        *reinterpret_cast<const float4*>(&waT[k * DD + c * 4]);
  }
  __syncthreads();
  // thread owns words wq*4..+3 (wq=tid&7), dims dq*2..+1 (dq=tid>>3, 0..31)
  int wq = tid & 7, dq = tid >> 3;
  float2 bias = *reinterpret_cast<const float2*>(&wa_b[dq * 2]);
  float acc[4][2];
#pragma unroll
  for (int i = 0; i < 4; ++i) { acc[i][0] = bias.x; acc[i][1] = bias.y; }
  for (int k = 0; k < DD; ++k) {
    float4 a4 = *reinterpret_cast<const float4*>(&A[k * 36 + wq * 4]);
    float2 b2v = *reinterpret_cast<const float2*>(&Bs[k * DD + dq * 2]);
    float av[4] = {a4.x, a4.y, a4.z, a4.w};
#pragma unroll
    for (int i = 0; i < 4; ++i) {
      acc[i][0] += av[i] * b2v.x;
      acc[i][1] += av[i] * b2v.y;
    }
  }
#pragma unroll
  for (int i = 0; i < 4; ++i) {
    acc[i][0] = fmaxf(acc[i][0], 0.f);
    acc[i][1] = fmaxf(acc[i][1], 0.f);
  }
#pragma unroll
  for (int i = 0; i < 4; ++i) {
    int v = v0 + wq * 4 + i;
    if (v < VV) {
      float2 r = {acc[i][0], acc[i][1]};
      *reinterpret_cast<float2*>(&E1[(size_t)v * DD + dq * 2]) = r;
    }
  }
  __syncthreads();
  // RsT[d][w] = relu; restage Bs = maT
#pragma unroll
  for (int j = 0; j < 2; ++j)
#pragma unroll
    for (int i = 0; i < 4; ++i)
      A[(dq * 2 + j) * 36 + wq * 4 + i] = acc[i][j];
  for (int i = tid; i < DD * 16; i += 256) {
    int k = i >> 4, c = i & 15;
    *reinterpret_cast<float4*>(&Bs[k * DD + c * 4]) =
        *reinterpret_cast<const float4*>(&maT[k * DD + c * 4]);
  }
  __syncthreads();
  float acc2[4][2];
#pragma unroll
  for (int i = 0; i < 4; ++i) { acc2[i][0] = 0.f; acc2[i][1] = 0.f; }
  for (int k = 0; k < DD; ++k) {
    float4 a4 = *reinterpret_cast<const float4*>(&A[k * 36 + wq * 4]);
    float2 b2v = *reinterpret_cast<const float2*>(&Bs[k * DD + dq * 2]);
    float av[4] = {a4.x, a4.y, a4.z, a4.w};
#pragma unroll
    for (int i = 0; i < 4; ++i) {
      acc2[i][0] += av[i] * b2v.x;
      acc2[i][1] += av[i] * b2v.y;
    }
  }
#pragma unroll
  for (int i = 0; i < 4; ++i) {
    int v = v0 + wq * 4 + i;
    if (v < VV) {
      float2 r = {acc2[i][0], acc2[i][1]};
      *reinterpret_cast<float2*>(&E2[(size_t)v * DD + dq * 2]) = r;
    }
  }
}

// ---------------- K2: review co-attention + gumbel selection (R10, bit-identical) ----------------
__global__ __launch_bounds__(256) void coatt_rev_sel(
    const float* __restrict__ u_rev, const float* __restrict__ i_rev,
    const float* __restrict__ raT, const float* __restrict__ ra_b,
    const float* __restrict__ ra_M, int* __restrict__ sel) {
  int b = blockIdx.x;
  __shared__ float ur[RR * 68], ir[RR * 68], uo[RR * 68], io[RR * 68], au[RR * 68];
  __shared__ float sc[RR * 21];
  __shared__ float rl[RR], cl[RR];
  __shared__ float gval[4][RR];
  int tid = threadIdx.x;
  for (int i = tid; i < RR * 16; i += 256) {
    int r = i >> 4, qq = i & 15;
    *reinterpret_cast<float4*>(&ur[r * 68 + qq * 4]) =
        *reinterpret_cast<const float4*>(&u_rev[(size_t)b * RR * DD + r * DD + qq * 4]);
    *reinterpret_cast<float4*>(&ir[r * 68 + qq * 4]) =
        *reinterpret_cast<const float4*>(&i_rev[(size_t)b * RR * DD + r * DD + qq * 4]);
  }
  __syncthreads();
  for (int s = tid; s < RR * 16; s += 256) {
    int u = s >> 4, q = s & 15;
    float4 bias = *reinterpret_cast<const float4*>(&ra_b[q * 4]);
    float4 a1 = bias, a2 = bias;
    for (int e = 0; e < DD; ++e) {
      float xu = ur[u * 68 + e];
      float xi = ir[u * 68 + e];
      float4 wv = *reinterpret_cast<const float4*>(&raT[e * DD + q * 4]);
      a1.x += xu * wv.x; a1.y += xu * wv.y; a1.z += xu * wv.z; a1.w += xu * wv.w;
      a2.x += xi * wv.x; a2.y += xi * wv.y; a2.z += xi * wv.z; a2.w += xi * wv.w;
    }
    a1.x = fmaxf(a1.x, 0.f); a1.y = fmaxf(a1.y, 0.f);
    a1.z = fmaxf(a1.z, 0.f); a1.w = fmaxf(a1.w, 0.f);
    a2.x = fmaxf(a2.x, 0.f); a2.y = fmaxf(a2.y, 0.f);
    a2.z = fmaxf(a2.z, 0.f); a2.w = fmaxf(a2.w, 0.f);
    *reinterpret_cast<float4*>(&uo[u * 68 + q * 4]) = a1;
    *reinterpret_cast<float4*>(&io[u * 68 + q * 4]) = a2;
  }
  __syncthreads();
  for (int s = tid; s < RR * 16; s += 256) {
    int u = s >> 4, q = s & 15;
    float4 a = {0.f, 0.f, 0.f, 0.f};
    for (int d2 = 0; d2 < DD; ++d2) {
      float xv = uo[u * 68 + d2];
      float4 mv = *reinterpret_cast<const float4*>(&ra_M[d2 * DD + q * 4]);
      a.x += xv * mv.x; a.y += xv * mv.y; a.z += xv * mv.z; a.w += xv * mv.w;
    }
    *reinterpret_cast<float4*>(&au[u * 68 + q * 4]) = a;
  }
  __syncthreads();
  for (int i = tid; i < RR * RR; i += 256) {
    int u = i / RR, v = i % RR;
    float a = 0.f;
    for (int e = 0; e < DD; ++e) a += au[u * 68 + e] * io[v * 68 + e];
    sc[u * 21 + v] = a;
  }
  __syncthreads();
  if (tid < RR) {
    float m = -INFINITY;
    for (int v = 0; v < RR; ++v) m = fmaxf(m, sc[tid * 21 + v]);
    rl[tid] = m;
  } else if (tid >= 64 && tid < 64 + RR) {
    int v = tid - 64;
    float m = -INFINITY;
    for (int u = 0; u < RR; ++u) m = fmaxf(m, sc[u * 21 + v]);
    cl[v] = m;
  }
  __syncthreads();
  if (tid < 4 * RR) {
    int n = tid / RR, r = tid % RR;
    uint32_t k0, k1, o0, o1;
    tf2x32(0u, 42u, 0u, (uint32_t)n, k0, k1);       // fold_in(key(42), n)
    int e = b * RR + r;
    tf2x32(k0, k1, 0u, (uint32_t)e, o0, o1);        // partitionable threefry
    uint32_t bits = o0 ^ o1;
    float u01 = __uint_as_float((bits >> 9) | 0x3f800000u) - 1.0f;
    const float TINY = 1.1754943508222875e-38f;
    float u = fmaxf(u01 + TINY, TINY);
    float g = -logf(-logf(u));
    gval[n][r] = ((n & 1) ? cl[r] : rl[r]) + g;
  }
  __syncthreads();
  if (tid < 4) {
    float best = -INFINITY; int arg = 0;
    for (int r = 0; r < RR; ++r) {                   // serial: first-max tie-break
      float v = gval[tid][r];
      if (v > best) { best = v; arg = r; }
    }
    sel[tid * BB + b] = arg;
  }
}

// ---------------- K3: word-level attention via tables (R10) ----------------
__global__ __launch_bounds__(256) void word_coatt(
    const int* __restrict__ uidx, const int* __restrict__ iidx,
    const float* __restrict__ emb,
    const float* __restrict__ E1, const float* __restrict__ E2,
    const int* __restrict__ sel, float* __restrict__ x) {
  int bid = blockIdx.x;
  int p = bid >> 9, b = bid & (BB - 1);
  int ru = sel[(2 * p) * BB + b];
  int rv = sel[(2 * p + 1) * BB + b];
  __shared__ int uw[LL], iw[LL];
  __shared__ float E1u[LL * 65], E2i[LL * 65];
  __shared__ float ubar[DD], zbar[DD];
  __shared__ float rm[LL], cm[LL];
  int tid = threadIdx.x;
  if (tid < LL) uw[tid] = uidx[((size_t)b * RR + ru) * LL + tid];
  else if (tid >= 64 && tid < 64 + LL) iw[tid - 64] = iidx[((size_t)b * RR + rv) * LL + (tid - 64)];
  __syncthreads();
  for (int i = tid; i < LL * DD; i += 256) {
    int l = i >> 6, d = i & 63;
    E1u[l * 65 + d] = E1[(size_t)uw[l] * DD + d];
    E2i[l * 65 + d] = E2[(size_t)iw[l] * DD + d];
  }
  __syncthreads();
  if (tid < DD) {
    float s = 0.f;
    for (int l = 0; l < LL; ++l) s += E1u[l * 65 + tid];
    ubar[tid] = s / 50.f;
  } else if (tid < 128) {
    int d = tid - 64;
    float s = 0.f;
    for (int l = 0; l < LL; ++l) s += E2i[l * 65 + d];
    zbar[d] = s / 50.f;
  }
  __syncthreads();
  if (tid < LL) {
    float a = 0.f;
    for (int e = 0; e < DD; ++e) a += E1u[tid * 65 + e] * zbar[e];
    rm[tid] = a;
  } else if (tid >= 64 && tid < 64 + LL) {
    int lj = tid - 64;
    float a = 0.f;
    for (int e = 0; e < DD; ++e) a += ubar[e] * E2i[lj * 65 + e];
    cm[lj] = a;
  }
  __syncthreads();
  int w = tid >> 6, lane = tid & 63;
  if (w == 0) {
    float v = (lane < LL) ? rm[lane] : -INFINITY;
    float m = wave_max(v);
    float ex = (lane < LL) ? expf(rm[lane] - m) : 0.f;
    float sm = wave_sum(ex);
    if (lane < LL) rm[lane] = ex / sm;
  } else if (w == 1) {
    float v = (lane < LL) ? cm[lane] : -INFINITY;
    float m = wave_max(v);
    float ex = (lane < LL) ? expf(cm[lane] - m) : 0.f;
    float sm = wave_sum(ex);
    if (lane < LL) cm[lane] = ex / sm;
  }
  __syncthreads();
  if (w == 0) {
    float a = 0.f;
    for (int l = 0; l < LL; ++l) a += rm[l] * emb[(size_t)uw[l] * DD + lane];
    x[(size_t)b * IN_DIM + p * DD + lane] = a;
  } else if (w == 1) {
    float a = 0.f;
    for (int l = 0; l < LL; ++l) a += cm[l] * emb[(size_t)iw[l] * DD + lane];
    x[(size_t)b * IN_DIM + 2 * DD + p * DD + lane] = a;
  }
}

// ---------------- K4: FM head (wave per sample) ----------------
__global__ __launch_bounds__(256) void fm_head(
    const float* __restrict__ x, const float* __restrict__ fm_v,
    const float* __restrict__ fm_w, const float* __restrict__ fm_b,
    float* __restrict__ out) {
  int tid = threadIdx.x;
  int w = tid >> 6, lane = tid & 63;
  int b = blockIdx.x * 4 + w;
  const float* xb = x + (size_t)b * IN_DIM;
  float4 xv4 = *reinterpret_cast<const float4*>(&xb[lane * 4]);
  float4 wv4 = *reinterpret_cast<const float4*>(&fm_w[lane * 4]);
  float xa[4] = {xv4.x, xv4.y, xv4.z, xv4.w};
  float wa[4] = {wv4.x, wv4.y, wv4.z, wv4.w};
  float lin = 0.f;
  float i1[KK], i2[KK];
#pragma unroll
  for (int k = 0; k < KK; ++k) { i1[k] = 0.f; i2[k] = 0.f; }
#pragma unroll
  for (int jj = 0; jj < 4; ++jj) {
    float xj = xa[jj];
    lin += xj * wa[jj];
    float x2 = xj * xj;
    const float* vr = fm_v + (size_t)(lane * 4 + jj) * KK;
#pragma unroll
    for (int k = 0; k < KK; ++k) {
      float v = vr[k];
      i1[k] += xj * v;
      i2[k] += x2 * (v * v);
    }
  }
  lin = wave_sum(lin);
  float pair = 0.f;
#pragma unroll
  for (int k = 0; k < KK; ++k) {
    float s1 = wave_sum(i1[k]);
    float s2 = wave_sum(i2[k]);
    pair += s1 * s1 - s2;
  }
  if (lane == 0) out[b] = (lin + fm_b[0]) + 0.5f * pair;
}

extern "C" void kernel_launch(void* const* d_in, const int* in_sizes, int n_in,
                              void* d_out, int out_size, void* d_ws, size_t ws_size,
                              hipStream_t stream) {
  (void)in_sizes; (void)n_in; (void)out_size; (void)ws_size;
  const int*   user_reviews = (const int*)d_in[0];
  const int*   item_reviews = (const int*)d_in[1];
  const float* emb  = (const float*)d_in[2];
  const float* gw1  = (const float*)d_in[3];
  const float* gw2  = (const float*)d_in[4];
  const float* gb2  = (const float*)d_in[5];
  const float* gbg  = (const float*)d_in[6];
  const float* ra_w = (const float*)d_in[7];
  const float* ra_b = (const float*)d_in[8];
  const float* ra_M = (const float*)d_in[9];
  const float* wa_w = (const float*)d_in[10];
  const float* wa_b = (const float*)d_in[11];
  const float* wa_M = (const float*)d_in[12];
  const float* fm_v = (const float*)d_in[13];
  const float* fm_w = (const float*)d_in[14];
  const float* fm_b = (const float*)d_in[15];
  float* out = (float*)d_out;

  float* ws = (float*)d_ws;
  float* u_rev = ws;                        // B*R*D = 655360
  float* i_rev = u_rev + BB * RR * DD;      // 655360
  float* x     = i_rev + BB * RR * DD;      // B*256 = 131072
  float* w1T   = x + BB * IN_DIM;           // 4096 each
  float* w2T   = w1T + DD * DD;
  float* raT   = w2T + DD * DD;
  float* waT   = raT + DD * DD;
  float* maT   = waT + DD * DD;
  float* E1    = maT + DD * DD;             // V*D = 3.2M
  float* E2    = E1 + (size_t)VV * DD;      // V*D = 3.2M
  int*   sel   = (int*)(E2 + (size_t)VV * DD);  // 4*B ints

  transpose_w<<<dim3(16), dim3(256), 0, stream>>>(gw1, gw2, ra_w, wa_w, wa_M,
                                                  w1T, w2T, raT, waT, maT);
  tables_embed<<<dim3(NEBLK + NTBLK), dim3(256), 0, stream>>>(
      user_reviews, item_reviews, emb, w1T, w2T, gb2, gbg,
      waT, wa_b, maT, u_rev, i_rev, E1, E2);
  coatt_rev_sel<<<dim3(BB), dim3(256), 0, stream>>>(
      u_rev, i_rev, raT, ra_b, ra_M, sel);
  word_coatt<<<dim3(PP * BB), dim3(256), 0, stream>>>(
      user_reviews, item_reviews, emb, E1, E2, sel, x);
  fm_head<<<dim3(128), dim3(256), 0, stream>>>(x, fm_v, fm_w, fm_b, out);
}

// Round 14
// 100.498 us; speedup vs baseline: 8.9055x; 8.9055x over previous
//
#include <hip/hip_runtime.h>
#include <stdint.h>
#include <math.h>

#define BB 512
#define RR 20
#define LL 50
#define DD 64
#define PP 2
#define KK 10
#define IN_DIM 256   // 2*P*D
#define VV 50000
#define NEBLK 1280   // embed blocks (16 reviews each)
#define NTBLK 782    // table-GEMM blocks (64 words each)

// ---------------- threefry2x32 (bit-exact JAX) ----------------
__device__ __forceinline__ uint32_t rotl32(uint32_t v, int d) {
  return (v << d) | (v >> (32 - d));
}

__device__ __forceinline__ void tf2x32(uint32_t k0, uint32_t k1,
                                       uint32_t x0, uint32_t x1,
                                       uint32_t& o0, uint32_t& o1) {
  uint32_t ks0 = k0, ks1 = k1, ks2 = k0 ^ k1 ^ 0x1BD11BDAu;
  x0 += ks0; x1 += ks1;
#define TF_RND(r) { x0 += x1; x1 = rotl32(x1, r); x1 ^= x0; }
  TF_RND(13) TF_RND(15) TF_RND(26) TF_RND(6)
  x0 += ks1; x1 += ks2 + 1u;
  TF_RND(17) TF_RND(29) TF_RND(16) TF_RND(24)
  x0 += ks2; x1 += ks0 + 2u;
  TF_RND(13) TF_RND(15) TF_RND(26) TF_RND(6)
  x0 += ks0; x1 += ks1 + 3u;
  TF_RND(17) TF_RND(29) TF_RND(16) TF_RND(24)
  x0 += ks1; x1 += ks2 + 4u;
  TF_RND(13) TF_RND(15) TF_RND(26) TF_RND(6)
  x0 += ks2; x1 += ks0 + 5u;
#undef TF_RND
  o0 = x0; o1 = x1;
}

__device__ __forceinline__ float wave_sum(float v) {
  for (int off = 32; off; off >>= 1) v += __shfl_xor(v, off, 64);
  return v;
}
__device__ __forceinline__ float wave_max(float v) {
  for (int off = 32; off; off >>= 1) v = fmaxf(v, __shfl_xor(v, off, 64));
  return v;
}

// ---------------- K0: transpose the 64x64 weight matrices ----------------
__global__ __launch_bounds__(256) void transpose_w(
    const float* __restrict__ w1, const float* __restrict__ w2,
    const float* __restrict__ ra, const float* __restrict__ wa,
    const float* __restrict__ ma,
    float* __restrict__ w1T, float* __restrict__ w2T,
    float* __restrict__ raT, float* __restrict__ waT,
    float* __restrict__ maT) {
  int i = blockIdx.x * 256 + threadIdx.x;
  if (i < DD * DD) {
    int r = i >> 6, c = i & 63;
    w1T[c * DD + r] = w1[i];
    w2T[c * DD + r] = w2[i];
    raT[c * DD + r] = ra[i];
    waT[c * DD + r] = wa[i];
    maT[c * DD + r] = ma[i];
  }
}

// ---------------- K1: FUSED embed_gate + build_tables (R10 + unpadded LDS) ----------------
// grid = NEBLK + NTBLK blocks, 256 threads. LDS = 32768 B -> 5 blocks/CU.
//   bid <  NEBLK : embed+gating (16 reviews; latency-bound gather)
//   bid >= NEBLK : table GEMM (64-word tile; VALU-bound) — co-resident filler.
// Bank notes (stride 64): GEMM A reads 2-way alias (free), Bs reads 4 distinct
// float4 (conflict-free), staging writes same-row consecutive (conflict-free);
// only the one-time RsT scatter is 8-way (negligible).
__global__ __launch_bounds__(256, 4) void tables_embed(
    const int* __restrict__ uidx, const int* __restrict__ iidx,
    const float* __restrict__ emb,
    const float* __restrict__ w1T, const float* __restrict__ w2T,
    const float* __restrict__ b2, const float* __restrict__ bg,
    const float* __restrict__ waT, const float* __restrict__ wa_b,
    const float* __restrict__ maT,
    float* __restrict__ u_rev, float* __restrict__ i_rev,
    float* __restrict__ E1, float* __restrict__ E2) {
  __shared__ float A[DD * DD / 4];   // 4096 floats: AsT[k][w] stride 64; reused as RsT
  __shared__ float Bs[DD * DD / 4];  // 4096 floats: B[k][d] stride 64
  int tid = threadIdx.x;
  int bid = blockIdx.x;

  if (bid < NEBLK) {
    // ======== embed + gating (R10 code, bit-identical math) ========
    int* idxs = (int*)A;                       // 800 ints
    float (*us)[68] = (float(*)[68])(A + 800); // 16 x 68 floats (1888 <= 4096)
    int isItem = (bid >= 640);
    const int* src = isItem ? (iidx + (size_t)(bid - 640) * 16 * LL)
                            : (uidx + (size_t)bid * 16 * LL);
    for (int i = tid; i < 16 * LL; i += 256) idxs[i] = src[i];
    __syncthreads();
    int w = tid >> 6, lane = tid & 63;
    int grp = lane >> 4, q = lane & 15;
    int revl = w * 4 + grp;
    const int* myidx = idxs + revl * LL;
    float4 acc = {0.f, 0.f, 0.f, 0.f};
#pragma unroll
    for (int l = 0; l < LL; ++l) {             // l-sequential (matches ref)
      int v = myidx[l];
      float4 e4 = *reinterpret_cast<const float4*>(&emb[(size_t)v * DD + q * 4]);
      acc.x += e4.x; acc.y += e4.y; acc.z += e4.z; acc.w += e4.w;
    }
    *reinterpret_cast<float4*>(&us[revl][q * 4]) = acc;
    __syncthreads();
    float4 d1 = {0.f, 0.f, 0.f, 0.f}, d2 = {0.f, 0.f, 0.f, 0.f};
    for (int e = 0; e < DD; ++e) {
      float xv = us[revl][e];                  // LDS broadcast
      float4 w1v = *reinterpret_cast<const float4*>(&w1T[e * DD + q * 4]);
      float4 w2v = *reinterpret_cast<const float4*>(&w2T[e * DD + q * 4]);
      d1.x += xv * w1v.x; d1.y += xv * w1v.y; d1.z += xv * w1v.z; d1.w += xv * w1v.w;
      d2.x += xv * w2v.x; d2.y += xv * w2v.y; d2.z += xv * w2v.z; d2.w += xv * w2v.w;
    }
    float4 b2v = *reinterpret_cast<const float4*>(&b2[q * 4]);
    float4 bgv = *reinterpret_cast<const float4*>(&bg[q * 4]);
    float4 val;
    val.x = 1.f / (1.f + expf(-d1.x)) + bgv.x * tanhf(d2.x + b2v.x);
    val.y = 1.f / (1.f + expf(-d1.y)) + bgv.y * tanhf(d2.y + b2v.y);
    val.z = 1.f / (1.f + expf(-d1.z)) + bgv.z * tanhf(d2.z + b2v.z);
    val.w = 1.f / (1.f + expf(-d1.w)) + bgv.w * tanhf(d2.w + b2v.w);
    int gid = bid * 16 + revl;
    int t = gid - isItem * (BB * RR);
    float* dst = isItem ? i_rev : u_rev;
    *reinterpret_cast<float4*>(&dst[(size_t)t * DD + q * 4]) = val;
    return;
  }

  // ======== table GEMM: E1 = relu(emb@waT+b), E2 = E1@maT (R10 code, stride 64) ========
  int v0 = (bid - NEBLK) * 64;
  {
    int wr = tid & 63;             // vocab row within tile
    int qk = tid >> 6;             // 0..3
    int v = v0 + wr;
    for (int rep = 0; rep < 4; ++rep) {
      int k0 = rep * 16 + qk * 4;
      float4 e4 = {0.f, 0.f, 0.f, 0.f};
      if (v < VV) e4 = *reinterpret_cast<const float4*>(&emb[(size_t)v * DD + k0]);
      A[(k0 + 0) * 64 + wr] = e4.x;
      A[(k0 + 1) * 64 + wr] = e4.y;
      A[(k0 + 2) * 64 + wr] = e4.z;
      A[(k0 + 3) * 64 + wr] = e4.w;
    }
  }
  for (int i = tid; i < DD * 16; i += 256) {
    int k = i >> 4, c = i & 15;
    *reinterpret_cast<float4*>(&Bs[k * 64 + c * 4]) =
        *reinterpret_cast<const float4*>(&waT[k * DD + c * 4]);
  }
  __syncthreads();
  int wq = tid & 15, dq = tid >> 4;
  float4 bias = *reinterpret_cast<const float4*>(&wa_b[dq * 4]);
  float acc[4][4];
#pragma unroll
  for (int i = 0; i < 4; ++i) {
    acc[i][0] = bias.x; acc[i][1] = bias.y; acc[i][2] = bias.z; acc[i][3] = bias.w;
  }
  for (int k = 0; k < DD; ++k) {
    float4 a4 = *reinterpret_cast<const float4*>(&A[k * 64 + wq * 4]);
    float4 b4 = *reinterpret_cast<const float4*>(&Bs[k * 64 + dq * 4]);
    float av[4] = {a4.x, a4.y, a4.z, a4.w};
    float bv[4] = {b4.x, b4.y, b4.z, b4.w};
#pragma unroll
    for (int i = 0; i < 4; ++i)
#pragma unroll
      for (int j = 0; j < 4; ++j) acc[i][j] += av[i] * bv[j];
  }
#pragma unroll
  for (int i = 0; i < 4; ++i)
#pragma unroll
    for (int j = 0; j < 4; ++j) acc[i][j] = fmaxf(acc[i][j], 0.f);
#pragma unroll
  for (int i = 0; i < 4; ++i) {
    int v = v0 + wq * 4 + i;
    if (v < VV) {
      float4 r = {acc[i][0], acc[i][1], acc[i][2], acc[i][3]};
      *reinterpret_cast<float4*>(&E1[(size_t)v * DD + dq * 4]) = r;
    }
  }
  __syncthreads();
#pragma unroll
  for (int j = 0; j < 4; ++j)
#pragma unroll
    for (int i = 0; i < 4; ++i)
      A[(dq * 4 + j) * 64 + wq * 4 + i] = acc[i][j];
  for (int i = tid; i < DD * 16; i += 256) {
    int k = i >> 4, c = i & 15;
    *reinterpret_cast<float4*>(&Bs[k * 64 + c * 4]) =
        *reinterpret_cast<const float4*>(&maT[k * DD + c * 4]);
  }
  __syncthreads();
  float acc2[4][4];
#pragma unroll
  for (int i = 0; i < 4; ++i)
#pragma unroll
    for (int j = 0; j < 4; ++j) acc2[i][j] = 0.f;
  for (int k = 0; k < DD; ++k) {
    float4 a4 = *reinterpret_cast<const float4*>(&A[k * 64 + wq * 4]);
    float4 b4 = *reinterpret_cast<const float4*>(&Bs[k * 64 + dq * 4]);
    float av[4] = {a4.x, a4.y, a4.z, a4.w};
    float bv[4] = {b4.x, b4.y, b4.z, b4.w};
#pragma unroll
    for (int i = 0; i < 4; ++i)
#pragma unroll
      for (int j = 0; j < 4; ++j) acc2[i][j] += av[i] * bv[j];
  }
#pragma unroll
  for (int i = 0; i < 4; ++i) {
    int v = v0 + wq * 4 + i;
    if (v < VV) {
      float4 r = {acc2[i][0], acc2[i][1], acc2[i][2], acc2[i][3]};
      *reinterpret_cast<float4*>(&E2[(size_t)v * DD + dq * 4]) = r;
    }
  }
}

// ---------------- K2: review co-attention + gumbel selection (R10, bit-identical) ----------------
__global__ __launch_bounds__(256) void coatt_rev_sel(
    const float* __restrict__ u_rev, const float* __restrict__ i_rev,
    const float* __restrict__ raT, const float* __restrict__ ra_b,
    const float* __restrict__ ra_M, int* __restrict__ sel) {
  int b = blockIdx.x;
  __shared__ float ur[RR * 68], ir[RR * 68], uo[RR * 68], io[RR * 68], au[RR * 68];
  __shared__ float sc[RR * 21];
  __shared__ float rl[RR], cl[RR];
  __shared__ float gval[4][RR];
  int tid = threadIdx.x;
  for (int i = tid; i < RR * 16; i += 256) {
    int r = i >> 4, qq = i & 15;
    *reinterpret_cast<float4*>(&ur[r * 68 + qq * 4]) =
        *reinterpret_cast<const float4*>(&u_rev[(size_t)b * RR * DD + r * DD + qq * 4]);
    *reinterpret_cast<float4*>(&ir[r * 68 + qq * 4]) =
        *reinterpret_cast<const float4*>(&i_rev[(size_t)b * RR * DD + r * DD + qq * 4]);
  }
  __syncthreads();
  for (int s = tid; s < RR * 16; s += 256) {
    int u = s >> 4, q = s & 15;
    float4 bias = *reinterpret_cast<const float4*>(&ra_b[q * 4]);
    float4 a1 = bias, a2 = bias;
    for (int e = 0; e < DD; ++e) {
      float xu = ur[u * 68 + e];
      float xi = ir[u * 68 + e];
      float4 wv = *reinterpret_cast<const float4*>(&raT[e * DD + q * 4]);
      a1.x += xu * wv.x; a1.y += xu * wv.y; a1.z += xu * wv.z; a1.w += xu * wv.w;
      a2.x += xi * wv.x; a2.y += xi * wv.y; a2.z += xi * wv.z; a2.w += xi * wv.w;
    }
    a1.x = fmaxf(a1.x, 0.f); a1.y = fmaxf(a1.y, 0.f);
    a1.z = fmaxf(a1.z, 0.f); a1.w = fmaxf(a1.w, 0.f);
    a2.x = fmaxf(a2.x, 0.f); a2.y = fmaxf(a2.y, 0.f);
    a2.z = fmaxf(a2.z, 0.f); a2.w = fmaxf(a2.w, 0.f);
    *reinterpret_cast<float4*>(&uo[u * 68 + q * 4]) = a1;
    *reinterpret_cast<float4*>(&io[u * 68 + q * 4]) = a2;
  }
  __syncthreads();
  for (int s = tid; s < RR * 16; s += 256) {
    int u = s >> 4, q = s & 15;
    float4 a = {0.f, 0.f, 0.f, 0.f};
    for (int d2 = 0; d2 < DD; ++d2) {
      float xv = uo[u * 68 + d2];
      float4 mv = *reinterpret_cast<const float4*>(&ra_M[d2 * DD + q * 4]);
      a.x += xv * mv.x; a.y += xv * mv.y; a.z += xv * mv.z; a.w += xv * mv.w;
    }
    *reinterpret_cast<float4*>(&au[u * 68 + q * 4]) = a;
  }
  __syncthreads();
  for (int i = tid; i < RR * RR; i += 256) {
    int u = i / RR, v = i % RR;
    float a = 0.f;
    for (int e = 0; e < DD; ++e) a += au[u * 68 + e] * io[v * 68 + e];
    sc[u * 21 + v] = a;
  }
  __syncthreads();
  if (tid < RR) {
    float m = -INFINITY;
    for (int v = 0; v < RR; ++v) m = fmaxf(m, sc[tid * 21 + v]);
    rl[tid] = m;
  } else if (tid >= 64 && tid < 64 + RR) {
    int v = tid - 64;
    float m = -INFINITY;
    for (int u = 0; u < RR; ++u) m = fmaxf(m, sc[u * 21 + v]);
    cl[v] = m;
  }
  __syncthreads();
  if (tid < 4 * RR) {
    int n = tid / RR, r = tid % RR;
    uint32_t k0, k1, o0, o1;
    tf2x32(0u, 42u, 0u, (uint32_t)n, k0, k1);       // fold_in(key(42), n)
    int e = b * RR + r;
    tf2x32(k0, k1, 0u, (uint32_t)e, o0, o1);        // partitionable threefry
    uint32_t bits = o0 ^ o1;
    float u01 = __uint_as_float((bits >> 9) | 0x3f800000u) - 1.0f;
    const float TINY = 1.1754943508222875e-38f;
    float u = fmaxf(u01 + TINY, TINY);
    float g = -logf(-logf(u));
    gval[n][r] = ((n & 1) ? cl[r] : rl[r]) + g;
  }
  __syncthreads();
  if (tid < 4) {
    float best = -INFINITY; int arg = 0;
    for (int r = 0; r < RR; ++r) {                   // serial: first-max tie-break
      float v = gval[tid][r];
      if (v > best) { best = v; arg = r; }
    }
    sel[tid * BB + b] = arg;
  }
}

// ---------------- K3: word-level attention via tables (R10) ----------------
__global__ __launch_bounds__(256) void word_coatt(
    const int* __restrict__ uidx, const int* __restrict__ iidx,
    const float* __restrict__ emb,
    const float* __restrict__ E1, const float* __restrict__ E2,
    const int* __restrict__ sel, float* __restrict__ x) {
  int bid = blockIdx.x;
  int p = bid >> 9, b = bid & (BB - 1);
  int ru = sel[(2 * p) * BB + b];
  int rv = sel[(2 * p + 1) * BB + b];
  __shared__ int uw[LL], iw[LL];
  __shared__ float E1u[LL * 65], E2i[LL * 65];
  __shared__ float ubar[DD], zbar[DD];
  __shared__ float rm[LL], cm[LL];
  int tid = threadIdx.x;
  if (tid < LL) uw[tid] = uidx[((size_t)b * RR + ru) * LL + tid];
  else if (tid >= 64 && tid < 64 + LL) iw[tid - 64] = iidx[((size_t)b * RR + rv) * LL + (tid - 64)];
  __syncthreads();
  for (int i = tid; i < LL * DD; i += 256) {
    int l = i >> 6, d = i & 63;
    E1u[l * 65 + d] = E1[(size_t)uw[l] * DD + d];
    E2i[l * 65 + d] = E2[(size_t)iw[l] * DD + d];
  }
  __syncthreads();
  if (tid < DD) {
    float s = 0.f;
    for (int l = 0; l < LL; ++l) s += E1u[l * 65 + tid];
    ubar[tid] = s / 50.f;
  } else if (tid < 128) {
    int d = tid - 64;
    float s = 0.f;
    for (int l = 0; l < LL; ++l) s += E2i[l * 65 + d];
    zbar[d] = s / 50.f;
  }
  __syncthreads();
  if (tid < LL) {
    float a = 0.f;
    for (int e = 0; e < DD; ++e) a += E1u[tid * 65 + e] * zbar[e];
    rm[tid] = a;
  } else if (tid >= 64 && tid < 64 + LL) {
    int lj = tid - 64;
    float a = 0.f;
    for (int e = 0; e < DD; ++e) a += ubar[e] * E2i[lj * 65 + e];
    cm[lj] = a;
  }
  __syncthreads();
  int w = tid >> 6, lane = tid & 63;
  if (w == 0) {
    float v = (lane < LL) ? rm[lane] : -INFINITY;
    float m = wave_max(v);
    float ex = (lane < LL) ? expf(rm[lane] - m) : 0.f;
    float sm = wave_sum(ex);
    if (lane < LL) rm[lane] = ex / sm;
  } else if (w == 1) {
    float v = (lane < LL) ? cm[lane] : -INFINITY;
    float m = wave_max(v);
    float ex = (lane < LL) ? expf(cm[lane] - m) : 0.f;
    float sm = wave_sum(ex);
    if (lane < LL) cm[lane] = ex / sm;
  }
  __syncthreads();
  if (w == 0) {
    float a = 0.f;
    for (int l = 0; l < LL; ++l) a += rm[l] * emb[(size_t)uw[l] * DD + lane];
    x[(size_t)b * IN_DIM + p * DD + lane] = a;
  } else if (w == 1) {
    float a = 0.f;
    for (int l = 0; l < LL; ++l) a += cm[l] * emb[(size_t)iw[l] * DD + lane];
    x[(size_t)b * IN_DIM + 2 * DD + p * DD + lane] = a;
  }
}

// ---------------- K4: FM head (wave per sample) ----------------
__global__ __launch_bounds__(256) void fm_head(
    const float* __restrict__ x, const float* __restrict__ fm_v,
    const float* __restrict__ fm_w, const float* __restrict__ fm_b,
    float* __restrict__ out) {
  int tid = threadIdx.x;
  int w = tid >> 6, lane = tid & 63;
  int b = blockIdx.x * 4 + w;
  const float* xb = x + (size_t)b * IN_DIM;
  float4 xv4 = *reinterpret_cast<const float4*>(&xb[lane * 4]);
  float4 wv4 = *reinterpret_cast<const float4*>(&fm_w[lane * 4]);
  float xa[4] = {xv4.x, xv4.y, xv4.z, xv4.w};
  float wa[4] = {wv4.x, wv4.y, wv4.z, wv4.w};
  float lin = 0.f;
  float i1[KK], i2[KK];
#pragma unroll
  for (int k = 0; k < KK; ++k) { i1[k] = 0.f; i2[k] = 0.f; }
#pragma unroll
  for (int jj = 0; jj < 4; ++jj) {
    float xj = xa[jj];
    lin += xj * wa[jj];
    float x2 = xj * xj;
    const float* vr = fm_v + (size_t)(lane * 4 + jj) * KK;
#pragma unroll
    for (int k = 0; k < KK; ++k) {
      float v = vr[k];
      i1[k] += xj * v;
      i2[k] += x2 * (v * v);
    }
  }
  lin = wave_sum(lin);
  float pair = 0.f;
#pragma unroll
  for (int k = 0; k < KK; ++k) {
    float s1 = wave_sum(i1[k]);
    float s2 = wave_sum(i2[k]);
    pair += s1 * s1 - s2;
  }
  if (lane == 0) out[b] = (lin + fm_b[0]) + 0.5f * pair;
}

extern "C" void kernel_launch(void* const* d_in, const int* in_sizes, int n_in,
                              void* d_out, int out_size, void* d_ws, size_t ws_size,
                              hipStream_t stream) {
  (void)in_sizes; (void)n_in; (void)out_size; (void)ws_size;
  const int*   user_reviews = (const int*)d_in[0];
  const int*   item_reviews = (const int*)d_in[1];
  const float* emb  = (const float*)d_in[2];
  const float* gw1  = (const float*)d_in[3];
  const float* gw2  = (const float*)d_in[4];
  const float* gb2  = (const float*)d_in[5];
  const float* gbg  = (const float*)d_in[6];
  const float* ra_w = (const float*)d_in[7];
  const float* ra_b = (const float*)d_in[8];
  const float* ra_M = (const float*)d_in[9];
  const float* wa_w = (const float*)d_in[10];
  const float* wa_b = (const float*)d_in[11];
  const float* wa_M = (const float*)d_in[12];
  const float* fm_v = (const float*)d_in[13];
  const float* fm_w = (const float*)d_in[14];
  const float* fm_b = (const float*)d_in[15];
  float* out = (float*)d_out;

  float* ws = (float*)d_ws;
  float* u_rev = ws;                        // B*R*D = 655360
  float* i_rev = u_rev + BB * RR * DD;      // 655360
  float* x     = i_rev + BB * RR * DD;      // B*256 = 131072
  float* w1T   = x + BB * IN_DIM;           // 4096 each
  float* w2T   = w1T + DD * DD;
  float* raT   = w2T + DD * DD;
  float* waT   = raT + DD * DD;
  float* maT   = waT + DD * DD;
  float* E1    = maT + DD * DD;             // V*D = 3.2M
  float* E2    = E1 + (size_t)VV * DD;      // V*D = 3.2M
  int*   sel   = (int*)(E2 + (size_t)VV * DD);  // 4*B ints

  transpose_w<<<dim3(16), dim3(256), 0, stream>>>(gw1, gw2, ra_w, wa_w, wa_M,
                                                  w1T, w2T, raT, waT, maT);
  tables_embed<<<dim3(NEBLK + NTBLK), dim3(256), 0, stream>>>(
      user_reviews, item_reviews, emb, w1T, w2T, gb2, gbg,
      waT, wa_b, maT, u_rev, i_rev, E1, E2);
  coatt_rev_sel<<<dim3(BB), dim3(256), 0, stream>>>(
      u_rev, i_rev, raT, ra_b, ra_M, sel);
  word_coatt<<<dim3(PP * BB), dim3(256), 0, stream>>>(
      user_reviews, item_reviews, emb, E1, E2, sel, x);
  fm_head<<<dim3(128), dim3(256), 0, stream>>>(x, fm_v, fm_w, fm_b, out);
}

// Round 15
// 99.731 us; speedup vs baseline: 8.9740x; 1.0077x over previous
//
#include <hip/hip_runtime.h>
#include <stdint.h>
#include <math.h>

#define BB 512
#define RR 20
#define LL 50
#define DD 64
#define PP 2
#define KK 10
#define IN_DIM 256   // 2*P*D
#define VV 50000
#define NEBLK 1280   // embed blocks (16 reviews each)
#define NTBLK 782    // table-GEMM blocks (64 words each)

// ---------------- threefry2x32 (bit-exact JAX) ----------------
__device__ __forceinline__ uint32_t rotl32(uint32_t v, int d) {
  return (v << d) | (v >> (32 - d));
}

__device__ __forceinline__ void tf2x32(uint32_t k0, uint32_t k1,
                                       uint32_t x0, uint32_t x1,
                                       uint32_t& o0, uint32_t& o1) {
  uint32_t ks0 = k0, ks1 = k1, ks2 = k0 ^ k1 ^ 0x1BD11BDAu;
  x0 += ks0; x1 += ks1;
#define TF_RND(r) { x0 += x1; x1 = rotl32(x1, r); x1 ^= x0; }
  TF_RND(13) TF_RND(15) TF_RND(26) TF_RND(6)
  x0 += ks1; x1 += ks2 + 1u;
  TF_RND(17) TF_RND(29) TF_RND(16) TF_RND(24)
  x0 += ks2; x1 += ks0 + 2u;
  TF_RND(13) TF_RND(15) TF_RND(26) TF_RND(6)
  x0 += ks0; x1 += ks1 + 3u;
  TF_RND(17) TF_RND(29) TF_RND(16) TF_RND(24)
  x0 += ks1; x1 += ks2 + 4u;
  TF_RND(13) TF_RND(15) TF_RND(26) TF_RND(6)
  x0 += ks2; x1 += ks0 + 5u;
#undef TF_RND
  o0 = x0; o1 = x1;
}

__device__ __forceinline__ float wave_sum(float v) {
  for (int off = 32; off; off >>= 1) v += __shfl_xor(v, off, 64);
  return v;
}
__device__ __forceinline__ float wave_max(float v) {
  for (int off = 32; off; off >>= 1) v = fmaxf(v, __shfl_xor(v, off, 64));
  return v;
}

// ---------------- K0: transpose the 64x64 weight matrices ----------------
__global__ __launch_bounds__(256) void transpose_w(
    const float* __restrict__ w1, const float* __restrict__ w2,
    const float* __restrict__ ra, const float* __restrict__ wa,
    const float* __restrict__ ma,
    float* __restrict__ w1T, float* __restrict__ w2T,
    float* __restrict__ raT, float* __restrict__ waT,
    float* __restrict__ maT) {
  int i = blockIdx.x * 256 + threadIdx.x;
  if (i < DD * DD) {
    int r = i >> 6, c = i & 63;
    w1T[c * DD + r] = w1[i];
    w2T[c * DD + r] = w2[i];
    raT[c * DD + r] = ra[i];
    waT[c * DD + r] = wa[i];
    maT[c * DD + r] = ma[i];
  }
}

// ---------------- K1: FUSED embed_gate + build_tables ----------------
// grid = NEBLK + NTBLK blocks, 256 threads. LDS = 2 x 16 KB = 32 KB -> 5 blocks/CU.
//   bid <  NEBLK : embed+gating (16 reviews; latency-bound gather)
//   bid >= NEBLK : table GEMM (64-word tile; VALU-bound) — co-resident filler.
// Bank notes (stride 64): GEMM A reads 2-way alias (free), Bs reads 4 distinct
// float4 (conflict-free), staging writes same-row consecutive (conflict-free);
// only the one-time RsT scatter is 8-way (negligible).
__global__ __launch_bounds__(256, 4) void tables_embed(
    const int* __restrict__ uidx, const int* __restrict__ iidx,
    const float* __restrict__ emb,
    const float* __restrict__ w1T, const float* __restrict__ w2T,
    const float* __restrict__ b2, const float* __restrict__ bg,
    const float* __restrict__ waT, const float* __restrict__ wa_b,
    const float* __restrict__ maT,
    float* __restrict__ u_rev, float* __restrict__ i_rev,
    float* __restrict__ E1, float* __restrict__ E2) {
  __shared__ float A[DD * 64];   // 4096 floats: AsT[k][w] stride 64; reused as RsT
  __shared__ float Bs[DD * 64];  // 4096 floats: B[k][d] stride 64
  int tid = threadIdx.x;
  int bid = blockIdx.x;

  if (bid < NEBLK) {
    // ======== embed + gating (R10 code, bit-identical math) ========
    int* idxs = (int*)A;                       // 800 ints
    float (*us)[68] = (float(*)[68])(A + 800); // 16 x 68 floats (1888 <= 4096)
    int isItem = (bid >= 640);
    const int* src = isItem ? (iidx + (size_t)(bid - 640) * 16 * LL)
                            : (uidx + (size_t)bid * 16 * LL);
    for (int i = tid; i < 16 * LL; i += 256) idxs[i] = src[i];
    __syncthreads();
    int w = tid >> 6, lane = tid & 63;
    int grp = lane >> 4, q = lane & 15;
    int revl = w * 4 + grp;
    const int* myidx = idxs + revl * LL;
    float4 acc = {0.f, 0.f, 0.f, 0.f};
#pragma unroll
    for (int l = 0; l < LL; ++l) {             // l-sequential (matches ref)
      int v = myidx[l];
      float4 e4 = *reinterpret_cast<const float4*>(&emb[(size_t)v * DD + q * 4]);
      acc.x += e4.x; acc.y += e4.y; acc.z += e4.z; acc.w += e4.w;
    }
    *reinterpret_cast<float4*>(&us[revl][q * 4]) = acc;
    __syncthreads();
    float4 d1 = {0.f, 0.f, 0.f, 0.f}, d2 = {0.f, 0.f, 0.f, 0.f};
    for (int e = 0; e < DD; ++e) {
      float xv = us[revl][e];                  // LDS broadcast
      float4 w1v = *reinterpret_cast<const float4*>(&w1T[e * DD + q * 4]);
      float4 w2v = *reinterpret_cast<const float4*>(&w2T[e * DD + q * 4]);
      d1.x += xv * w1v.x; d1.y += xv * w1v.y; d1.z += xv * w1v.z; d1.w += xv * w1v.w;
      d2.x += xv * w2v.x; d2.y += xv * w2v.y; d2.z += xv * w2v.z; d2.w += xv * w2v.w;
    }
    float4 b2v = *reinterpret_cast<const float4*>(&b2[q * 4]);
    float4 bgv = *reinterpret_cast<const float4*>(&bg[q * 4]);
    float4 val;
    val.x = 1.f / (1.f + expf(-d1.x)) + bgv.x * tanhf(d2.x + b2v.x);
    val.y = 1.f / (1.f + expf(-d1.y)) + bgv.y * tanhf(d2.y + b2v.y);
    val.z = 1.f / (1.f + expf(-d1.z)) + bgv.z * tanhf(d2.z + b2v.z);
    val.w = 1.f / (1.f + expf(-d1.w)) + bgv.w * tanhf(d2.w + b2v.w);
    int gid = bid * 16 + revl;
    int t = gid - isItem * (BB * RR);
    float* dst = isItem ? i_rev : u_rev;
    *reinterpret_cast<float4*>(&dst[(size_t)t * DD + q * 4]) = val;
    return;
  }

  // ======== table GEMM: E1 = relu(emb@waT+b), E2 = E1@maT (R10 math, stride 64) ========
  int v0 = (bid - NEBLK) * 64;
  {
    int wr = tid & 63;             // vocab row within tile
    int qk = tid >> 6;             // 0..3
    int v = v0 + wr;
    for (int rep = 0; rep < 4; ++rep) {
      int k0 = rep * 16 + qk * 4;
      float4 e4 = {0.f, 0.f, 0.f, 0.f};
      if (v < VV) e4 = *reinterpret_cast<const float4*>(&emb[(size_t)v * DD + k0]);
      A[(k0 + 0) * 64 + wr] = e4.x;
      A[(k0 + 1) * 64 + wr] = e4.y;
      A[(k0 + 2) * 64 + wr] = e4.z;
      A[(k0 + 3) * 64 + wr] = e4.w;
    }
  }
  for (int i = tid; i < DD * 16; i += 256) {
    int k = i >> 4, c = i & 15;
    *reinterpret_cast<float4*>(&Bs[k * 64 + c * 4]) =
        *reinterpret_cast<const float4*>(&waT[k * DD + c * 4]);
  }
  __syncthreads();
  int wq = tid & 15, dq = tid >> 4;
  float4 bias = *reinterpret_cast<const float4*>(&wa_b[dq * 4]);
  float acc[4][4];
#pragma unroll
  for (int i = 0; i < 4; ++i) {
    acc[i][0] = bias.x; acc[i][1] = bias.y; acc[i][2] = bias.z; acc[i][3] = bias.w;
  }
  for (int k = 0; k < DD; ++k) {
    float4 a4 = *reinterpret_cast<const float4*>(&A[k * 64 + wq * 4]);
    float4 b4 = *reinterpret_cast<const float4*>(&Bs[k * 64 + dq * 4]);
    float av[4] = {a4.x, a4.y, a4.z, a4.w};
    float bv[4] = {b4.x, b4.y, b4.z, b4.w};
#pragma unroll
    for (int i = 0; i < 4; ++i)
#pragma unroll
      for (int j = 0; j < 4; ++j) acc[i][j] += av[i] * bv[j];
  }
#pragma unroll
  for (int i = 0; i < 4; ++i)
#pragma unroll
    for (int j = 0; j < 4; ++j) acc[i][j] = fmaxf(acc[i][j], 0.f);
#pragma unroll
  for (int i = 0; i < 4; ++i) {
    int v = v0 + wq * 4 + i;
    if (v < VV) {
      float4 r = {acc[i][0], acc[i][1], acc[i][2], acc[i][3]};
      *reinterpret_cast<float4*>(&E1[(size_t)v * DD + dq * 4]) = r;
    }
  }
  __syncthreads();
#pragma unroll
  for (int j = 0; j < 4; ++j)
#pragma unroll
    for (int i = 0; i < 4; ++i)
      A[(dq * 4 + j) * 64 + wq * 4 + i] = acc[i][j];
  for (int i = tid; i < DD * 16; i += 256) {
    int k = i >> 4, c = i & 15;
    *reinterpret_cast<float4*>(&Bs[k * 64 + c * 4]) =
        *reinterpret_cast<const float4*>(&maT[k * DD + c * 4]);
  }
  __syncthreads();
  float acc2[4][4];
#pragma unroll
  for (int i = 0; i < 4; ++i)
#pragma unroll
    for (int j = 0; j < 4; ++j) acc2[i][j] = 0.f;
  for (int k = 0; k < DD; ++k) {
    float4 a4 = *reinterpret_cast<const float4*>(&A[k * 64 + wq * 4]);
    float4 b4 = *reinterpret_cast<const float4*>(&Bs[k * 64 + dq * 4]);
    float av[4] = {a4.x, a4.y, a4.z, a4.w};
    float bv[4] = {b4.x, b4.y, b4.z, b4.w};
#pragma unroll
    for (int i = 0; i < 4; ++i)
#pragma unroll
      for (int j = 0; j < 4; ++j) acc2[i][j] += av[i] * bv[j];
  }
#pragma unroll
  for (int i = 0; i < 4; ++i) {
    int v = v0 + wq * 4 + i;
    if (v < VV) {
      float4 r = {acc2[i][0], acc2[i][1], acc2[i][2], acc2[i][3]};
      *reinterpret_cast<float4*>(&E2[(size_t)v * DD + dq * 4]) = r;
    }
  }
}

// ---------------- K2: review co-attention + gumbel selection (R10, bit-identical) ----------------
__global__ __launch_bounds__(256) void coatt_rev_sel(
    const float* __restrict__ u_rev, const float* __restrict__ i_rev,
    const float* __restrict__ raT, const float* __restrict__ ra_b,
    const float* __restrict__ ra_M, int* __restrict__ sel) {
  int b = blockIdx.x;
  __shared__ float ur[RR * 68], ir[RR * 68], uo[RR * 68], io[RR * 68], au[RR * 68];
  __shared__ float sc[RR * 21];
  __shared__ float rl[RR], cl[RR];
  __shared__ float gval[4][RR];
  int tid = threadIdx.x;
  for (int i = tid; i < RR * 16; i += 256) {
    int r = i >> 4, qq = i & 15;
    *reinterpret_cast<float4*>(&ur[r * 68 + qq * 4]) =
        *reinterpret_cast<const float4*>(&u_rev[(size_t)b * RR * DD + r * DD + qq * 4]);
    *reinterpret_cast<float4*>(&ir[r * 68 + qq * 4]) =
        *reinterpret_cast<const float4*>(&i_rev[(size_t)b * RR * DD + r * DD + qq * 4]);
  }
  __syncthreads();
  for (int s = tid; s < RR * 16; s += 256) {
    int u = s >> 4, q = s & 15;
    float4 bias = *reinterpret_cast<const float4*>(&ra_b[q * 4]);
    float4 a1 = bias, a2 = bias;
    for (int e = 0; e < DD; ++e) {
      float xu = ur[u * 68 + e];
      float xi = ir[u * 68 + e];
      float4 wv = *reinterpret_cast<const float4*>(&raT[e * DD + q * 4]);
      a1.x += xu * wv.x; a1.y += xu * wv.y; a1.z += xu * wv.z; a1.w += xu * wv.w;
      a2.x += xi * wv.x; a2.y += xi * wv.y; a2.z += xi * wv.z; a2.w += xi * wv.w;
    }
    a1.x = fmaxf(a1.x, 0.f); a1.y = fmaxf(a1.y, 0.f);
    a1.z = fmaxf(a1.z, 0.f); a1.w = fmaxf(a1.w, 0.f);
    a2.x = fmaxf(a2.x, 0.f); a2.y = fmaxf(a2.y, 0.f);
    a2.z = fmaxf(a2.z, 0.f); a2.w = fmaxf(a2.w, 0.f);
    *reinterpret_cast<float4*>(&uo[u * 68 + q * 4]) = a1;
    *reinterpret_cast<float4*>(&io[u * 68 + q * 4]) = a2;
  }
  __syncthreads();
  for (int s = tid; s < RR * 16; s += 256) {
    int u = s >> 4, q = s & 15;
    float4 a = {0.f, 0.f, 0.f, 0.f};
    for (int d2 = 0; d2 < DD; ++d2) {
      float xv = uo[u * 68 + d2];
      float4 mv = *reinterpret_cast<const float4*>(&ra_M[d2 * DD + q * 4]);
      a.x += xv * mv.x; a.y += xv * mv.y; a.z += xv * mv.z; a.w += xv * mv.w;
    }
    *reinterpret_cast<float4*>(&au[u * 68 + q * 4]) = a;
  }
  __syncthreads();
  for (int i = tid; i < RR * RR; i += 256) {
    int u = i / RR, v = i % RR;
    float a = 0.f;
    for (int e = 0; e < DD; ++e) a += au[u * 68 + e] * io[v * 68 + e];
    sc[u * 21 + v] = a;
  }
  __syncthreads();
  if (tid < RR) {
    float m = -INFINITY;
    for (int v = 0; v < RR; ++v) m = fmaxf(m, sc[tid * 21 + v]);
    rl[tid] = m;
  } else if (tid >= 64 && tid < 64 + RR) {
    int v = tid - 64;
    float m = -INFINITY;
    for (int u = 0; u < RR; ++u) m = fmaxf(m, sc[u * 21 + v]);
    cl[v] = m;
  }
  __syncthreads();
  if (tid < 4 * RR) {
    int n = tid / RR, r = tid % RR;
    uint32_t k0, k1, o0, o1;
    tf2x32(0u, 42u, 0u, (uint32_t)n, k0, k1);       // fold_in(key(42), n)
    int e = b * RR + r;
    tf2x32(k0, k1, 0u, (uint32_t)e, o0, o1);        // partitionable threefry
    uint32_t bits = o0 ^ o1;
    float u01 = __uint_as_float((bits >> 9) | 0x3f800000u) - 1.0f;
    const float TINY = 1.1754943508222875e-38f;
    float u = fmaxf(u01 + TINY, TINY);
    float g = -logf(-logf(u));
    gval[n][r] = ((n & 1) ? cl[r] : rl[r]) + g;
  }
  __syncthreads();
  if (tid < 4) {
    float best = -INFINITY; int arg = 0;
    for (int r = 0; r < RR; ++r) {                   // serial: first-max tie-break
      float v = gval[tid][r];
      if (v > best) { best = v; arg = r; }
    }
    sel[tid * BB + b] = arg;
  }
}

// ---------------- K3: word-level attention via tables (R10) ----------------
__global__ __launch_bounds__(256) void word_coatt(
    const int* __restrict__ uidx, const int* __restrict__ iidx,
    const float* __restrict__ emb,
    const float* __restrict__ E1, const float* __restrict__ E2,
    const int* __restrict__ sel, float* __restrict__ x) {
  int bid = blockIdx.x;
  int p = bid >> 9, b = bid & (BB - 1);
  int ru = sel[(2 * p) * BB + b];
  int rv = sel[(2 * p + 1) * BB + b];
  __shared__ int uw[LL], iw[LL];
  __shared__ float E1u[LL * 65], E2i[LL * 65];
  __shared__ float ubar[DD], zbar[DD];
  __shared__ float rm[LL], cm[LL];
  int tid = threadIdx.x;
  if (tid < LL) uw[tid] = uidx[((size_t)b * RR + ru) * LL + tid];
  else if (tid >= 64 && tid < 64 + LL) iw[tid - 64] = iidx[((size_t)b * RR + rv) * LL + (tid - 64)];
  __syncthreads();
  for (int i = tid; i < LL * DD; i += 256) {
    int l = i >> 6, d = i & 63;
    E1u[l * 65 + d] = E1[(size_t)uw[l] * DD + d];
    E2i[l * 65 + d] = E2[(size_t)iw[l] * DD + d];
  }
  __syncthreads();
  if (tid < DD) {
    float s = 0.f;
    for (int l = 0; l < LL; ++l) s += E1u[l * 65 + tid];
    ubar[tid] = s / 50.f;
  } else if (tid < 128) {
    int d = tid - 64;
    float s = 0.f;
    for (int l = 0; l < LL; ++l) s += E2i[l * 65 + d];
    zbar[d] = s / 50.f;
  }
  __syncthreads();
  if (tid < LL) {
    float a = 0.f;
    for (int e = 0; e < DD; ++e) a += E1u[tid * 65 + e] * zbar[e];
    rm[tid] = a;
  } else if (tid >= 64 && tid < 64 + LL) {
    int lj = tid - 64;
    float a = 0.f;
    for (int e = 0; e < DD; ++e) a += ubar[e] * E2i[lj * 65 + e];
    cm[lj] = a;
  }
  __syncthreads();
  int w = tid >> 6, lane = tid & 63;
  if (w == 0) {
    float v = (lane < LL) ? rm[lane] : -INFINITY;
    float m = wave_max(v);
    float ex = (lane < LL) ? expf(rm[lane] - m) : 0.f;
    float sm = wave_sum(ex);
    if (lane < LL) rm[lane] = ex / sm;
  } else if (w == 1) {
    float v = (lane < LL) ? cm[lane] : -INFINITY;
    float m = wave_max(v);
    float ex = (lane < LL) ? expf(cm[lane] - m) : 0.f;
    float sm = wave_sum(ex);
    if (lane < LL) cm[lane] = ex / sm;
  }
  __syncthreads();
  if (w == 0) {
    float a = 0.f;
    for (int l = 0; l < LL; ++l) a += rm[l] * emb[(size_t)uw[l] * DD + lane];
    x[(size_t)b * IN_DIM + p * DD + lane] = a;
  } else if (w == 1) {
    float a = 0.f;
    for (int l = 0; l < LL; ++l) a += cm[l] * emb[(size_t)iw[l] * DD + lane];
    x[(size_t)b * IN_DIM + 2 * DD + p * DD + lane] = a;
  }
}

// ---------------- K4: FM head (wave per sample) ----------------
__global__ __launch_bounds__(256) void fm_head(
    const float* __restrict__ x, const float* __restrict__ fm_v,
    const float* __restrict__ fm_w, const float* __restrict__ fm_b,
    float* __restrict__ out) {
  int tid = threadIdx.x;
  int w = tid >> 6, lane = tid & 63;
  int b = blockIdx.x * 4 + w;
  const float* xb = x + (size_t)b * IN_DIM;
  float4 xv4 = *reinterpret_cast<const float4*>(&xb[lane * 4]);
  float4 wv4 = *reinterpret_cast<const float4*>(&fm_w[lane * 4]);
  float xa[4] = {xv4.x, xv4.y, xv4.z, xv4.w};
  float wa[4] = {wv4.x, wv4.y, wv4.z, wv4.w};
  float lin = 0.f;
  float i1[KK], i2[KK];
#pragma unroll
  for (int k = 0; k < KK; ++k) { i1[k] = 0.f; i2[k] = 0.f; }
#pragma unroll
  for (int jj = 0; jj < 4; ++jj) {
    float xj = xa[jj];
    lin += xj * wa[jj];
    float x2 = xj * xj;
    const float* vr = fm_v + (size_t)(lane * 4 + jj) * KK;
#pragma unroll
    for (int k = 0; k < KK; ++k) {
      float v = vr[k];
      i1[k] += xj * v;
      i2[k] += x2 * (v * v);
    }
  }
  lin = wave_sum(lin);
  float pair = 0.f;
#pragma unroll
  for (int k = 0; k < KK; ++k) {
    float s1 = wave_sum(i1[k]);
    float s2 = wave_sum(i2[k]);
    pair += s1 * s1 - s2;
  }
  if (lane == 0) out[b] = (lin + fm_b[0]) + 0.5f * pair;
}

extern "C" void kernel_launch(void* const* d_in, const int* in_sizes, int n_in,
                              void* d_out, int out_size, void* d_ws, size_t ws_size,
                              hipStream_t stream) {
  (void)in_sizes; (void)n_in; (void)out_size; (void)ws_size;
  const int*   user_reviews = (const int*)d_in[0];
  const int*   item_reviews = (const int*)d_in[1];
  const float* emb  = (const float*)d_in[2];
  const float* gw1  = (const float*)d_in[3];
  const float* gw2  = (const float*)d_in[4];
  const float* gb2  = (const float*)d_in[5];
  const float* gbg  = (const float*)d_in[6];
  const float* ra_w = (const float*)d_in[7];
  const float* ra_b = (const float*)d_in[8];
  const float* ra_M = (const float*)d_in[9];
  const float* wa_w = (const float*)d_in[10];
  const float* wa_b = (const float*)d_in[11];
  const float* wa_M = (const float*)d_in[12];
  const float* fm_v = (const float*)d_in[13];
  const float* fm_w = (const float*)d_in[14];
  const float* fm_b = (const float*)d_in[15];
  float* out = (float*)d_out;

  float* ws = (float*)d_ws;
  float* u_rev = ws;                        // B*R*D = 655360
  float* i_rev = u_rev + BB * RR * DD;      // 655360
  float* x     = i_rev + BB * RR * DD;      // B*256 = 131072
  float* w1T   = x + BB * IN_DIM;           // 4096 each
  float* w2T   = w1T + DD * DD;
  float* raT   = w2T + DD * DD;
  float* waT   = raT + DD * DD;
  float* maT   = waT + DD * DD;
  float* E1    = maT + DD * DD;             // V*D = 3.2M
  float* E2    = E1 + (size_t)VV * DD;      // V*D = 3.2M
  int*   sel   = (int*)(E2 + (size_t)VV * DD);  // 4*B ints

  transpose_w<<<dim3(16), dim3(256), 0, stream>>>(gw1, gw2, ra_w, wa_w, wa_M,
                                                  w1T, w2T, raT, waT, maT);
  tables_embed<<<dim3(NEBLK + NTBLK), dim3(256), 0, stream>>>(
      user_reviews, item_reviews, emb, w1T, w2T, gb2, gbg,
      waT, wa_b, maT, u_rev, i_rev, E1, E2);
  coatt_rev_sel<<<dim3(BB), dim3(256), 0, stream>>>(
      u_rev, i_rev, raT, ra_b, ra_M, sel);
  word_coatt<<<dim3(PP * BB), dim3(256), 0, stream>>>(
      user_reviews, item_reviews, emb, E1, E2, sel, x);
  fm_head<<<dim3(128), dim3(256), 0, stream>>>(x, fm_v, fm_w, fm_b, out);
}

// Round 16
// 98.490 us; speedup vs baseline: 9.0870x; 1.0126x over previous
//
#include <hip/hip_runtime.h>
#include <stdint.h>
#include <math.h>

#define BB 512
#define RR 20
#define LL 50
#define DD 64
#define PP 2
#define KK 10
#define IN_DIM 256   // 2*P*D
#define VV 50000
#define NEBLK 1280   // embed blocks (16 reviews each)
#define NTBLK 782    // table-GEMM blocks (64 words each)

// ---------------- threefry2x32 (bit-exact JAX) ----------------
__device__ __forceinline__ uint32_t rotl32(uint32_t v, int d) {
  return (v << d) | (v >> (32 - d));
}

__device__ __forceinline__ void tf2x32(uint32_t k0, uint32_t k1,
                                       uint32_t x0, uint32_t x1,
                                       uint32_t& o0, uint32_t& o1) {
  uint32_t ks0 = k0, ks1 = k1, ks2 = k0 ^ k1 ^ 0x1BD11BDAu;
  x0 += ks0; x1 += ks1;
#define TF_RND(r) { x0 += x1; x1 = rotl32(x1, r); x1 ^= x0; }
  TF_RND(13) TF_RND(15) TF_RND(26) TF_RND(6)
  x0 += ks1; x1 += ks2 + 1u;
  TF_RND(17) TF_RND(29) TF_RND(16) TF_RND(24)
  x0 += ks2; x1 += ks0 + 2u;
  TF_RND(13) TF_RND(15) TF_RND(26) TF_RND(6)
  x0 += ks0; x1 += ks1 + 3u;
  TF_RND(17) TF_RND(29) TF_RND(16) TF_RND(24)
  x0 += ks1; x1 += ks2 + 4u;
  TF_RND(13) TF_RND(15) TF_RND(26) TF_RND(6)
  x0 += ks2; x1 += ks0 + 5u;
#undef TF_RND
  o0 = x0; o1 = x1;
}

__device__ __forceinline__ float wave_sum(float v) {
  for (int off = 32; off; off >>= 1) v += __shfl_xor(v, off, 64);
  return v;
}
__device__ __forceinline__ float wave_max(float v) {
  for (int off = 32; off; off >>= 1) v = fmaxf(v, __shfl_xor(v, off, 64));
  return v;
}

// ---------------- K0: transpose the 64x64 weight matrices ----------------
__global__ __launch_bounds__(256) void transpose_w(
    const float* __restrict__ w1, const float* __restrict__ w2,
    const float* __restrict__ ra, const float* __restrict__ wa,
    const float* __restrict__ ma,
    float* __restrict__ w1T, float* __restrict__ w2T,
    float* __restrict__ raT, float* __restrict__ waT,
    float* __restrict__ maT) {
  int i = blockIdx.x * 256 + threadIdx.x;
  if (i < DD * DD) {
    int r = i >> 6, c = i & 63;
    w1T[c * DD + r] = w1[i];
    w2T[c * DD + r] = w2[i];
    raT[c * DD + r] = ra[i];
    waT[c * DD + r] = wa[i];
    maT[c * DD + r] = ma[i];
  }
}

// ---------------- K1: FUSED embed_gate + build_tables (R15, unchanged) ----------------
__global__ __launch_bounds__(256, 4) void tables_embed(
    const int* __restrict__ uidx, const int* __restrict__ iidx,
    const float* __restrict__ emb,
    const float* __restrict__ w1T, const float* __restrict__ w2T,
    const float* __restrict__ b2, const float* __restrict__ bg,
    const float* __restrict__ waT, const float* __restrict__ wa_b,
    const float* __restrict__ maT,
    float* __restrict__ u_rev, float* __restrict__ i_rev,
    float* __restrict__ E1, float* __restrict__ E2) {
  __shared__ float A[DD * 64];   // 4096 floats: AsT[k][w] stride 64; reused as RsT
  __shared__ float Bs[DD * 64];  // 4096 floats: B[k][d] stride 64
  int tid = threadIdx.x;
  int bid = blockIdx.x;

  if (bid < NEBLK) {
    // ======== embed + gating (bit-identical math) ========
    int* idxs = (int*)A;                       // 800 ints
    float (*us)[68] = (float(*)[68])(A + 800); // 16 x 68 floats (1888 <= 4096)
    int isItem = (bid >= 640);
    const int* src = isItem ? (iidx + (size_t)(bid - 640) * 16 * LL)
                            : (uidx + (size_t)bid * 16 * LL);
    for (int i = tid; i < 16 * LL; i += 256) idxs[i] = src[i];
    __syncthreads();
    int w = tid >> 6, lane = tid & 63;
    int grp = lane >> 4, q = lane & 15;
    int revl = w * 4 + grp;
    const int* myidx = idxs + revl * LL;
    float4 acc = {0.f, 0.f, 0.f, 0.f};
#pragma unroll
    for (int l = 0; l < LL; ++l) {             // l-sequential (matches ref)
      int v = myidx[l];
      float4 e4 = *reinterpret_cast<const float4*>(&emb[(size_t)v * DD + q * 4]);
      acc.x += e4.x; acc.y += e4.y; acc.z += e4.z; acc.w += e4.w;
    }
    *reinterpret_cast<float4*>(&us[revl][q * 4]) = acc;
    __syncthreads();
    float4 d1 = {0.f, 0.f, 0.f, 0.f}, d2 = {0.f, 0.f, 0.f, 0.f};
    for (int e = 0; e < DD; ++e) {
      float xv = us[revl][e];                  // LDS broadcast
      float4 w1v = *reinterpret_cast<const float4*>(&w1T[e * DD + q * 4]);
      float4 w2v = *reinterpret_cast<const float4*>(&w2T[e * DD + q * 4]);
      d1.x += xv * w1v.x; d1.y += xv * w1v.y; d1.z += xv * w1v.z; d1.w += xv * w1v.w;
      d2.x += xv * w2v.x; d2.y += xv * w2v.y; d2.z += xv * w2v.z; d2.w += xv * w2v.w;
    }
    float4 b2v = *reinterpret_cast<const float4*>(&b2[q * 4]);
    float4 bgv = *reinterpret_cast<const float4*>(&bg[q * 4]);
    float4 val;
    val.x = 1.f / (1.f + expf(-d1.x)) + bgv.x * tanhf(d2.x + b2v.x);
    val.y = 1.f / (1.f + expf(-d1.y)) + bgv.y * tanhf(d2.y + b2v.y);
    val.z = 1.f / (1.f + expf(-d1.z)) + bgv.z * tanhf(d2.z + b2v.z);
    val.w = 1.f / (1.f + expf(-d1.w)) + bgv.w * tanhf(d2.w + b2v.w);
    int gid = bid * 16 + revl;
    int t = gid - isItem * (BB * RR);
    float* dst = isItem ? i_rev : u_rev;
    *reinterpret_cast<float4*>(&dst[(size_t)t * DD + q * 4]) = val;
    return;
  }

  // ======== table GEMM: E1 = relu(emb@waT+b), E2 = E1@maT ========
  int v0 = (bid - NEBLK) * 64;
  {
    int wr = tid & 63;             // vocab row within tile
    int qk = tid >> 6;             // 0..3
    int v = v0 + wr;
    for (int rep = 0; rep < 4; ++rep) {
      int k0 = rep * 16 + qk * 4;
      float4 e4 = {0.f, 0.f, 0.f, 0.f};
      if (v < VV) e4 = *reinterpret_cast<const float4*>(&emb[(size_t)v * DD + k0]);
      A[(k0 + 0) * 64 + wr] = e4.x;
      A[(k0 + 1) * 64 + wr] = e4.y;
      A[(k0 + 2) * 64 + wr] = e4.z;
      A[(k0 + 3) * 64 + wr] = e4.w;
    }
  }
  for (int i = tid; i < DD * 16; i += 256) {
    int k = i >> 4, c = i & 15;
    *reinterpret_cast<float4*>(&Bs[k * 64 + c * 4]) =
        *reinterpret_cast<const float4*>(&waT[k * DD + c * 4]);
  }
  __syncthreads();
  int wq = tid & 15, dq = tid >> 4;
  float4 bias = *reinterpret_cast<const float4*>(&wa_b[dq * 4]);
  float acc[4][4];
#pragma unroll
  for (int i = 0; i < 4; ++i) {
    acc[i][0] = bias.x; acc[i][1] = bias.y; acc[i][2] = bias.z; acc[i][3] = bias.w;
  }
  for (int k = 0; k < DD; ++k) {
    float4 a4 = *reinterpret_cast<const float4*>(&A[k * 64 + wq * 4]);
    float4 b4 = *reinterpret_cast<const float4*>(&Bs[k * 64 + dq * 4]);
    float av[4] = {a4.x, a4.y, a4.z, a4.w};
    float bv[4] = {b4.x, b4.y, b4.z, b4.w};
#pragma unroll
    for (int i = 0; i < 4; ++i)
#pragma unroll
      for (int j = 0; j < 4; ++j) acc[i][j] += av[i] * bv[j];
  }
#pragma unroll
  for (int i = 0; i < 4; ++i)
#pragma unroll
    for (int j = 0; j < 4; ++j) acc[i][j] = fmaxf(acc[i][j], 0.f);
#pragma unroll
  for (int i = 0; i < 4; ++i) {
    int v = v0 + wq * 4 + i;
    if (v < VV) {
      float4 r = {acc[i][0], acc[i][1], acc[i][2], acc[i][3]};
      *reinterpret_cast<float4*>(&E1[(size_t)v * DD + dq * 4]) = r;
    }
  }
  __syncthreads();
#pragma unroll
  for (int j = 0; j < 4; ++j)
#pragma unroll
    for (int i = 0; i < 4; ++i)
      A[(dq * 4 + j) * 64 + wq * 4 + i] = acc[i][j];
  for (int i = tid; i < DD * 16; i += 256) {
    int k = i >> 4, c = i & 15;
    *reinterpret_cast<float4*>(&Bs[k * 64 + c * 4]) =
        *reinterpret_cast<const float4*>(&maT[k * DD + c * 4]);
  }
  __syncthreads();
  float acc2[4][4];
#pragma unroll
  for (int i = 0; i < 4; ++i)
#pragma unroll
    for (int j = 0; j < 4; ++j) acc2[i][j] = 0.f;
  for (int k = 0; k < DD; ++k) {
    float4 a4 = *reinterpret_cast<const float4*>(&A[k * 64 + wq * 4]);
    float4 b4 = *reinterpret_cast<const float4*>(&Bs[k * 64 + dq * 4]);
    float av[4] = {a4.x, a4.y, a4.z, a4.w};
    float bv[4] = {b4.x, b4.y, b4.z, b4.w};
#pragma unroll
    for (int i = 0; i < 4; ++i)
#pragma unroll
      for (int j = 0; j < 4; ++j) acc2[i][j] += av[i] * bv[j];
  }
#pragma unroll
  for (int i = 0; i < 4; ++i) {
    int v = v0 + wq * 4 + i;
    if (v < VV) {
      float4 r = {acc2[i][0], acc2[i][1], acc2[i][2], acc2[i][3]};
      *reinterpret_cast<float4*>(&E2[(size_t)v * DD + dq * 4]) = r;
    }
  }
}

// ---------------- K2: review co-attention + gumbel selection (bit-identical) ----------------
__global__ __launch_bounds__(256) void coatt_rev_sel(
    const float* __restrict__ u_rev, const float* __restrict__ i_rev,
    const float* __restrict__ raT, const float* __restrict__ ra_b,
    const float* __restrict__ ra_M, int* __restrict__ sel) {
  int b = blockIdx.x;
  __shared__ float ur[RR * 68], ir[RR * 68], uo[RR * 68], io[RR * 68], au[RR * 68];
  __shared__ float sc[RR * 21];
  __shared__ float rl[RR], cl[RR];
  __shared__ float gval[4][RR];
  int tid = threadIdx.x;
  for (int i = tid; i < RR * 16; i += 256) {
    int r = i >> 4, qq = i & 15;
    *reinterpret_cast<float4*>(&ur[r * 68 + qq * 4]) =
        *reinterpret_cast<const float4*>(&u_rev[(size_t)b * RR * DD + r * DD + qq * 4]);
    *reinterpret_cast<float4*>(&ir[r * 68 + qq * 4]) =
        *reinterpret_cast<const float4*>(&i_rev[(size_t)b * RR * DD + r * DD + qq * 4]);
  }
  __syncthreads();
  for (int s = tid; s < RR * 16; s += 256) {
    int u = s >> 4, q = s & 15;
    float4 bias = *reinterpret_cast<const float4*>(&ra_b[q * 4]);
    float4 a1 = bias, a2 = bias;
    for (int e = 0; e < DD; ++e) {
      float xu = ur[u * 68 + e];
      float xi = ir[u * 68 + e];
      float4 wv = *reinterpret_cast<const float4*>(&raT[e * DD + q * 4]);
      a1.x += xu * wv.x; a1.y += xu * wv.y; a1.z += xu * wv.z; a1.w += xu * wv.w;
      a2.x += xi * wv.x; a2.y += xi * wv.y; a2.z += xi * wv.z; a2.w += xi * wv.w;
    }
    a1.x = fmaxf(a1.x, 0.f); a1.y = fmaxf(a1.y, 0.f);
    a1.z = fmaxf(a1.z, 0.f); a1.w = fmaxf(a1.w, 0.f);
    a2.x = fmaxf(a2.x, 0.f); a2.y = fmaxf(a2.y, 0.f);
    a2.z = fmaxf(a2.z, 0.f); a2.w = fmaxf(a2.w, 0.f);
    *reinterpret_cast<float4*>(&uo[u * 68 + q * 4]) = a1;
    *reinterpret_cast<float4*>(&io[u * 68 + q * 4]) = a2;
  }
  __syncthreads();
  for (int s = tid; s < RR * 16; s += 256) {
    int u = s >> 4, q = s & 15;
    float4 a = {0.f, 0.f, 0.f, 0.f};
    for (int d2 = 0; d2 < DD; ++d2) {
      float xv = uo[u * 68 + d2];
      float4 mv = *reinterpret_cast<const float4*>(&ra_M[d2 * DD + q * 4]);
      a.x += xv * mv.x; a.y += xv * mv.y; a.z += xv * mv.z; a.w += xv * mv.w;
    }
    *reinterpret_cast<float4*>(&au[u * 68 + q * 4]) = a;
  }
  __syncthreads();
  for (int i = tid; i < RR * RR; i += 256) {
    int u = i / RR, v = i % RR;
    float a = 0.f;
    for (int e = 0; e < DD; ++e) a += au[u * 68 + e] * io[v * 68 + e];
    sc[u * 21 + v] = a;
  }
  __syncthreads();
  if (tid < RR) {
    float m = -INFINITY;
    for (int v = 0; v < RR; ++v) m = fmaxf(m, sc[tid * 21 + v]);
    rl[tid] = m;
  } else if (tid >= 64 && tid < 64 + RR) {
    int v = tid - 64;
    float m = -INFINITY;
    for (int u = 0; u < RR; ++u) m = fmaxf(m, sc[u * 21 + v]);
    cl[v] = m;
  }
  __syncthreads();
  if (tid < 4 * RR) {
    int n = tid / RR, r = tid % RR;
    uint32_t k0, k1, o0, o1;
    tf2x32(0u, 42u, 0u, (uint32_t)n, k0, k1);       // fold_in(key(42), n)
    int e = b * RR + r;
    tf2x32(k0, k1, 0u, (uint32_t)e, o0, o1);        // partitionable threefry
    uint32_t bits = o0 ^ o1;
    float u01 = __uint_as_float((bits >> 9) | 0x3f800000u) - 1.0f;
    const float TINY = 1.1754943508222875e-38f;
    float u = fmaxf(u01 + TINY, TINY);
    float g = -logf(-logf(u));
    gval[n][r] = ((n & 1) ? cl[r] : rl[r]) + g;
  }
  __syncthreads();
  if (tid < 4) {
    float best = -INFINITY; int arg = 0;
    for (int r = 0; r < RR; ++r) {                   // serial: first-max tie-break
      float v = gval[tid][r];
      if (v > best) { best = v; arg = r; }
    }
    sel[tid * BB + b] = arg;
  }
}

// ---------------- K3: FUSED word-level attention (both p in parallel) + FM head ----------------
// grid = B blocks, 512 threads. Threads [0,256) -> p=0, [256,512) -> p=1,
// each half running the exact word_coatt code on its own LDS region.
// Final x[256] stays in LDS; wave 0 computes the FM head (same math as R15).
// LDS ~55 KB -> 2 blocks/CU (16 waves/CU, same TLP class as before).
__global__ __launch_bounds__(512) void word_fm(
    const int* __restrict__ uidx, const int* __restrict__ iidx,
    const float* __restrict__ emb,
    const float* __restrict__ E1, const float* __restrict__ E2,
    const int* __restrict__ sel,
    const float* __restrict__ fm_v, const float* __restrict__ fm_w,
    const float* __restrict__ fm_b, float* __restrict__ out) {
  int b = blockIdx.x;
  int tid = threadIdx.x;
  int p = tid >> 8;          // 0 or 1
  int t = tid & 255;         // local thread in half
  __shared__ int uw[2][LL], iw[2][LL];
  __shared__ float E1u[2][LL * 65], E2i[2][LL * 65];
  __shared__ float ubar[2][DD], zbar[2][DD];
  __shared__ float rm[2][LL], cm[2][LL];
  __shared__ float xb[IN_DIM];

  int ru = sel[(2 * p) * BB + b];
  int rv = sel[(2 * p + 1) * BB + b];
  if (t < LL) uw[p][t] = uidx[((size_t)b * RR + ru) * LL + t];
  else if (t >= 64 && t < 64 + LL) iw[p][t - 64] = iidx[((size_t)b * RR + rv) * LL + (t - 64)];
  __syncthreads();
  for (int i = t; i < LL * DD; i += 256) {
    int l = i >> 6, d = i & 63;
    E1u[p][l * 65 + d] = E1[(size_t)uw[p][l] * DD + d];
    E2i[p][l * 65 + d] = E2[(size_t)iw[p][l] * DD + d];
  }
  __syncthreads();
  if (t < DD) {
    float s = 0.f;
    for (int l = 0; l < LL; ++l) s += E1u[p][l * 65 + t];
    ubar[p][t] = s / 50.f;
  } else if (t < 128) {
    int d = t - 64;
    float s = 0.f;
    for (int l = 0; l < LL; ++l) s += E2i[p][l * 65 + d];
    zbar[p][d] = s / 50.f;
  }
  __syncthreads();
  if (t < LL) {
    float a = 0.f;
    for (int e = 0; e < DD; ++e) a += E1u[p][t * 65 + e] * zbar[p][e];
    rm[p][t] = a;
  } else if (t >= 64 && t < 64 + LL) {
    int lj = t - 64;
    float a = 0.f;
    for (int e = 0; e < DD; ++e) a += ubar[p][e] * E2i[p][lj * 65 + e];
    cm[p][lj] = a;
  }
  __syncthreads();
  int lw = t >> 6, lane = t & 63;     // local wave within half
  if (lw == 0) {
    float v = (lane < LL) ? rm[p][lane] : -INFINITY;
    float m = wave_max(v);
    float ex = (lane < LL) ? expf(rm[p][lane] - m) : 0.f;
    float sm = wave_sum(ex);
    if (lane < LL) rm[p][lane] = ex / sm;
  } else if (lw == 1) {
    float v = (lane < LL) ? cm[p][lane] : -INFINITY;
    float m = wave_max(v);
    float ex = (lane < LL) ? expf(cm[p][lane] - m) : 0.f;
    float sm = wave_sum(ex);
    if (lane < LL) cm[p][lane] = ex / sm;
  }
  __syncthreads();
  // x layout: [u_p0 | u_p1 | i_p0 | i_p1]
  if (lw == 0) {
    float a = 0.f;
    for (int l = 0; l < LL; ++l) a += rm[p][l] * emb[(size_t)uw[p][l] * DD + lane];
    xb[p * DD + lane] = a;
  } else if (lw == 1) {
    float a = 0.f;
    for (int l = 0; l < LL; ++l) a += cm[p][l] * emb[(size_t)iw[p][l] * DD + lane];
    xb[2 * DD + p * DD + lane] = a;
  }
  __syncthreads();
  // ---- FM head (wave 0; identical math to R15's fm_head) ----
  if (tid < 64) {
    float4 xv4 = *reinterpret_cast<const float4*>(&xb[tid * 4]);
    float4 wv4 = *reinterpret_cast<const float4*>(&fm_w[tid * 4]);
    float xa[4] = {xv4.x, xv4.y, xv4.z, xv4.w};
    float wa[4] = {wv4.x, wv4.y, wv4.z, wv4.w};
    float lin = 0.f;
    float i1[KK], i2[KK];
#pragma unroll
    for (int k = 0; k < KK; ++k) { i1[k] = 0.f; i2[k] = 0.f; }
#pragma unroll
    for (int jj = 0; jj < 4; ++jj) {
      float xj = xa[jj];
      lin += xj * wa[jj];
      float x2 = xj * xj;
      const float* vr = fm_v + (size_t)(tid * 4 + jj) * KK;
#pragma unroll
      for (int k = 0; k < KK; ++k) {
        float v = vr[k];
        i1[k] += xj * v;
        i2[k] += x2 * (v * v);
      }
    }
    lin = wave_sum(lin);
    float pair = 0.f;
#pragma unroll
    for (int k = 0; k < KK; ++k) {
      float s1 = wave_sum(i1[k]);
      float s2 = wave_sum(i2[k]);
      pair += s1 * s1 - s2;
    }
    if (tid == 0) out[b] = (lin + fm_b[0]) + 0.5f * pair;
  }
}

extern "C" void kernel_launch(void* const* d_in, const int* in_sizes, int n_in,
                              void* d_out, int out_size, void* d_ws, size_t ws_size,
                              hipStream_t stream) {
  (void)in_sizes; (void)n_in; (void)out_size; (void)ws_size;
  const int*   user_reviews = (const int*)d_in[0];
  const int*   item_reviews = (const int*)d_in[1];
  const float* emb  = (const float*)d_in[2];
  const float* gw1  = (const float*)d_in[3];
  const float* gw2  = (const float*)d_in[4];
  const float* gb2  = (const float*)d_in[5];
  const float* gbg  = (const float*)d_in[6];
  const float* ra_w = (const float*)d_in[7];
  const float* ra_b = (const float*)d_in[8];
  const float* ra_M = (const float*)d_in[9];
  const float* wa_w = (const float*)d_in[10];
  const float* wa_b = (const float*)d_in[11];
  const float* wa_M = (const float*)d_in[12];
  const float* fm_v = (const float*)d_in[13];
  const float* fm_w = (const float*)d_in[14];
  const float* fm_b = (const float*)d_in[15];
  float* out = (float*)d_out;

  float* ws = (float*)d_ws;
  float* u_rev = ws;                        // B*R*D = 655360
  float* i_rev = u_rev + BB * RR * DD;      // 655360
  float* w1T   = i_rev + BB * RR * DD;      // 4096 each
  float* w2T   = w1T + DD * DD;
  float* raT   = w2T + DD * DD;
  float* waT   = raT + DD * DD;
  float* maT   = waT + DD * DD;
  float* E1    = maT + DD * DD;             // V*D = 3.2M
  float* E2    = E1 + (size_t)VV * DD;      // V*D = 3.2M
  int*   sel   = (int*)(E2 + (size_t)VV * DD);  // 4*B ints

  transpose_w<<<dim3(16), dim3(256), 0, stream>>>(gw1, gw2, ra_w, wa_w, wa_M,
                                                  w1T, w2T, raT, waT, maT);
  tables_embed<<<dim3(NEBLK + NTBLK), dim3(256), 0, stream>>>(
      user_reviews, item_reviews, emb, w1T, w2T, gb2, gbg,
      waT, wa_b, maT, u_rev, i_rev, E1, E2);
  coatt_rev_sel<<<dim3(BB), dim3(256), 0, stream>>>(
      u_rev, i_rev, raT, ra_b, ra_M, sel);
  word_fm<<<dim3(BB), dim3(512), 0, stream>>>(
      user_reviews, item_reviews, emb, E1, E2, sel,
      fm_v, fm_w, fm_b, out);
}